// Round 12
// baseline (475.344 us; speedup 1.0000x reference)
//
#include <hip/hip_runtime.h>
#include <math.h>

#define D 256
#define SCAN_CHUNK 1024
#define GPITCH 264    // bf16 LDS pitch for MFMA A tiles (pad 8) — verified pattern r3-r10
#define UVPITCH 520   // bf16 pitch per query region: 256 u | 256 v | 8 pad (1040 B, 16B-aligned)
#define LP_BLOCKS 512 // persistent linkpred grid: 2 blocks/CU

typedef __attribute__((ext_vector_type(8))) short frag_ab;   // 8 bf16
typedef __attribute__((ext_vector_type(4))) float frag_cd;   // 4 fp32

__device__ inline unsigned short f2b(float f) {
    unsigned int u = __float_as_uint(f);
    u += 0x7fffu + ((u >> 16) & 1u);
    return (unsigned short)(u >> 16);
}
__device__ inline float b2f(unsigned short h) {
    return __uint_as_float(((unsigned int)h) << 16);
}
// elementwise product of two packed bf16 pairs -> packed bf16 pair (TRUNCATING, 7 VALU ops)
__device__ inline unsigned int bmul2t(unsigned int a, unsigned int b) {
    float a0 = __uint_as_float(a << 16);
    float a1 = __uint_as_float(a & 0xffff0000u);
    float b0 = __uint_as_float(b << 16);
    float b1 = __uint_as_float(b & 0xffff0000u);
    float p0 = a0 * b0, p1 = a1 * b1;
    return __builtin_amdgcn_perm(__float_as_uint(p1), __float_as_uint(p0), 0x07060302);
}

// async global->LDS, 16B per lane; LDS dest = wave-uniform base + lane*16
__device__ inline void async_ld16(const void* g, void* l) {
    __builtin_amdgcn_global_load_lds(
        (const __attribute__((address_space(1))) void*)g,
        (__attribute__((address_space(3))) void*)l,
        16, 0, 0);
}

// ---------- zero int buffer ----------
__global__ void k_zero_int(int* p, int n) {
    int i = blockIdx.x * 256 + threadIdx.x;
    if (i < n) p[i] = 0;
}

// ---------- int degree count ----------
__global__ void k_count_int(const int* __restrict__ row, int* deg, int E) {
    int e = blockIdx.x * 256 + threadIdx.x;
    if (e < E) atomicAdd(&deg[row[e]], 1);
}

// ---------- prefix scan (3 stages); excl written into rowptr ----------
__global__ __launch_bounds__(256) void k_scan_block(const int* __restrict__ deg, int* __restrict__ excl,
                                                    int* __restrict__ bsums, int n) {
    __shared__ int s[256];
    int blk = blockIdx.x, t = threadIdx.x;
    int base = blk * SCAN_CHUNK + t * 4;
    int v0 = (base + 0 < n) ? deg[base + 0] : 0;
    int v1 = (base + 1 < n) ? deg[base + 1] : 0;
    int v2 = (base + 2 < n) ? deg[base + 2] : 0;
    int v3 = (base + 3 < n) ? deg[base + 3] : 0;
    int tsum = v0 + v1 + v2 + v3;
    s[t] = tsum;
    __syncthreads();
    for (int off = 1; off < 256; off <<= 1) {
        int x = (t >= off) ? s[t - off] : 0;
        __syncthreads();
        s[t] += x;
        __syncthreads();
    }
    int run = s[t] - tsum;
    if (t == 255) bsums[blk] = s[255];
    if (base + 0 < n) excl[base + 0] = run;
    run += v0;
    if (base + 1 < n) excl[base + 1] = run;
    run += v1;
    if (base + 2 < n) excl[base + 2] = run;
    run += v2;
    if (base + 3 < n) excl[base + 3] = run;
}

__global__ __launch_bounds__(256) void k_scan_bsums(int* bsums, int nb) {
    __shared__ int s[256];
    int t = threadIdx.x;
    int v = (t < nb) ? bsums[t] : 0;
    s[t] = v;
    __syncthreads();
    for (int off = 1; off < 256; off <<= 1) {
        int x = (t >= off) ? s[t - off] : 0;
        __syncthreads();
        s[t] += x;
        __syncthreads();
    }
    if (t < nb) bsums[t] = s[t] - v;
}

// fused: rowptr[i] += bsums[i/SCAN_CHUNK]  AND  dinv[i] = rsqrt(deg[i]+1)
__global__ void k_scan_add_dinv(int* __restrict__ rowptr, const int* __restrict__ bsums,
                                const int* __restrict__ deg, float* __restrict__ dinv,
                                int n, int total) {
    int i = blockIdx.x * 256 + threadIdx.x;
    if (i < n) {
        rowptr[i] += bsums[i / SCAN_CHUNK];
        dinv[i] = rsqrtf((float)(deg[i] + 1));
    }
    if (i == 0) rowptr[n] = total;
}

// ---------- bucket edges into CSR ----------
__global__ void k_bucket(const int* __restrict__ row, const int* __restrict__ col,
                         const int* __restrict__ rowptr, int* __restrict__ fill,
                         int* __restrict__ ebuf, int E) {
    int e = blockIdx.x * 256 + threadIdx.x;
    if (e >= E) return;
    int r = row[e];
    int pos = atomicAdd(&fill[r], 1);
    ebuf[rowptr[r] + pos] = col[e];
}

// ---------- pack three fp32 [k][n] weights into MFMA B-fragment order (bf16) ----------
__global__ void k_packB3(const float* __restrict__ Wa, const float* __restrict__ Wb,
                         const float* __restrict__ Wc,
                         unsigned short* __restrict__ Ba, unsigned short* __restrict__ Bb,
                         unsigned short* __restrict__ Bc) {
    int which = blockIdx.x >> 8;
    int i = (blockIdx.x & 255) * 256 + threadIdx.x;   // 65536 per weight
    const float* W = (which == 0) ? Wa : (which == 1) ? Wb : Wc;
    unsigned short* Bp = (which == 0) ? Ba : (which == 1) ? Bb : Bc;
    int ntile = i >> 12;
    int kt = (i >> 9) & 7;
    int lane = (i >> 3) & 63;
    int j = i & 7;
    int k = kt * 32 + (lane >> 4) * 8 + j;
    int n = ntile * 16 + (lane & 15);
    Bp[i] = f2b(W[k * D + n]);
}

// ---------- MFMA GEMM: 32-row tile (r10 version — best measured) ----------
__global__ __launch_bounds__(256) void k_gemm_mfma(const void* __restrict__ X, int xIsF32,
                                                   const unsigned short* __restrict__ Bpack,
                                                   unsigned short* __restrict__ H, int nrows) {
    __shared__ unsigned short As[32 * GPITCH];
    int t = threadIdx.x;
    int rowBase = blockIdx.x * 32;

    {
        int half = t >> 7;
        int cpair = t & 127;
        for (int qi = 0; qi < 32; qi += 2) {
            int q = qi + half;
            int r = rowBase + q;
            unsigned int val = 0;
            if (r < nrows) {
                if (xIsF32) {
                    const float* xr = (const float*)X + (size_t)r * D + cpair * 2;
                    val = (unsigned int)f2b(xr[0]) | ((unsigned int)f2b(xr[1]) << 16);
                } else {
                    val = ((const unsigned int*)((const unsigned short*)X + (size_t)r * D))[cpair];
                }
            }
            *(unsigned int*)&As[q * GPITCH + cpair * 2] = val;
        }
    }
    __syncthreads();

    int w = t >> 6, lane = t & 63;
    int mtile = w >> 1;
    int nhalf = w & 1;
    int quad = lane >> 4, lcol = lane & 15;

    frag_cd acc[8];
    #pragma unroll
    for (int n = 0; n < 8; ++n) acc[n] = (frag_cd){0.f, 0.f, 0.f, 0.f};

    const frag_ab* bp = (const frag_ab*)Bpack;
    for (int kt = 0; kt < 8; ++kt) {
        frag_ab a = *(const frag_ab*)&As[(mtile * 16 + lcol) * GPITCH + kt * 32 + quad * 8];
        #pragma unroll
        for (int n = 0; n < 8; ++n) {
            frag_ab b = bp[((nhalf * 8 + n) * 8 + kt) * 64 + lane];
            acc[n] = __builtin_amdgcn_mfma_f32_16x16x32_bf16(a, b, acc[n], 0, 0, 0);
        }
    }

    #pragma unroll
    for (int n = 0; n < 8; ++n) {
        int col = (nhalf * 8 + n) * 16 + lcol;
        #pragma unroll
        for (int r = 0; r < 4; ++r) {
            int row = rowBase + mtile * 16 + quad * 4 + r;
            if (row < nrows) H[(size_t)row * D + col] = f2b(acc[n][r]);
        }
    }
}

// ---------- aggregate by gather: 2 nodes per wave, 32 lanes (16B) per node ----------
__device__ inline void fma8(uint4 p, float nw, float* a) {
    a[0] = fmaf(b2f((unsigned short)(p.x & 0xffffu)), nw, a[0]);
    a[1] = fmaf(b2f((unsigned short)(p.x >> 16)),     nw, a[1]);
    a[2] = fmaf(b2f((unsigned short)(p.y & 0xffffu)), nw, a[2]);
    a[3] = fmaf(b2f((unsigned short)(p.y >> 16)),     nw, a[3]);
    a[4] = fmaf(b2f((unsigned short)(p.z & 0xffffu)), nw, a[4]);
    a[5] = fmaf(b2f((unsigned short)(p.z >> 16)),     nw, a[5]);
    a[6] = fmaf(b2f((unsigned short)(p.w & 0xffffu)), nw, a[6]);
    a[7] = fmaf(b2f((unsigned short)(p.w >> 16)),     nw, a[7]);
}

__global__ __launch_bounds__(256) void k_agg(const unsigned short* __restrict__ Hh,
                                             const int* __restrict__ rowptr, const int* __restrict__ ebuf,
                                             const float* __restrict__ dinv, const float* __restrict__ b,
                                             unsigned short* __restrict__ Xo, int n, int relu) {
    int w = threadIdx.x >> 6, lane = threadIdx.x & 63;
    int half = lane >> 5, sub = lane & 31;
    int node = (blockIdx.x * 4 + w) * 2 + half;
    if (node >= n) return;
    int c8 = sub * 8;

    float dn = dinv[node];
    float self = dn * dn;

    float acc[8];
    {
        uint4 hp = *(const uint4*)&Hh[(size_t)node * D + c8];
        float4 b0 = *(const float4*)&b[c8];
        float4 b1 = *(const float4*)&b[c8 + 4];
        acc[0] = b0.x; acc[1] = b0.y; acc[2] = b0.z; acc[3] = b0.w;
        acc[4] = b1.x; acc[5] = b1.y; acc[6] = b1.z; acc[7] = b1.w;
        fma8(hp, self, acc);
    }

    int beg = rowptr[node], end = rowptr[node + 1];
    int j = beg;
    for (; j + 3 < end; j += 4) {
        int cA = ebuf[j], cB = ebuf[j + 1], cC = ebuf[j + 2], cD = ebuf[j + 3];
        float nA = dn * dinv[cA], nB = dn * dinv[cB], nC = dn * dinv[cC], nD = dn * dinv[cD];
        uint4 pA = *(const uint4*)&Hh[(size_t)cA * D + c8];
        uint4 pB = *(const uint4*)&Hh[(size_t)cB * D + c8];
        uint4 pC = *(const uint4*)&Hh[(size_t)cC * D + c8];
        uint4 pD = *(const uint4*)&Hh[(size_t)cD * D + c8];
        fma8(pA, nA, acc);
        fma8(pB, nB, acc);
        fma8(pC, nC, acc);
        fma8(pD, nD, acc);
    }
    for (; j < end; ++j) {
        int cA = ebuf[j];
        uint4 pA = *(const uint4*)&Hh[(size_t)cA * D + c8];
        fma8(pA, dn * dinv[cA], acc);
    }
    if (relu) {
        #pragma unroll
        for (int i = 0; i < 8; ++i) acc[i] = fmaxf(acc[i], 0.f);
    }
    uint4 pk;
    pk.x = (unsigned int)f2b(acc[0]) | ((unsigned int)f2b(acc[1]) << 16);
    pk.y = (unsigned int)f2b(acc[2]) | ((unsigned int)f2b(acc[3]) << 16);
    pk.z = (unsigned int)f2b(acc[4]) | ((unsigned int)f2b(acc[5]) << 16);
    pk.w = (unsigned int)f2b(acc[6]) | ((unsigned int)f2b(acc[7]) << 16);
    *(uint4*)&Xo[(size_t)node * D + c8] = pk;
}

// ---------- link predictor: PERSISTENT + double-buffered async staging ----------
// Grid-strided over 32-query tiles. While computing tile i from UV[b], the loads for
// tile i+LP_BLOCKS are in flight into UV[b^1]; wait is vmcnt(8) (leaves newest 8 in
// flight) instead of a full drain. 2 blocks/CU (66.6 KB LDS).
__global__ __launch_bounds__(256) void k_linkpred(const int* __restrict__ u, const int* __restrict__ v,
                                                  const unsigned short* __restrict__ X16,
                                                  const unsigned short* __restrict__ Bpack,
                                                  const float* __restrict__ P1b,
                                                  const float* __restrict__ P2w, const float* __restrict__ P2b,
                                                  float* __restrict__ out, int Q, int ntiles) {
    __shared__ unsigned short UV[2][32 * UVPITCH];   // 2 x 33,280 B
    __shared__ float red[4][32];

    int t = threadIdx.x;
    int w = t >> 6, lane = t & 63;
    int quad = lane >> 4, lcol = lane & 15;

    // wave-invariant epilogue constants
    float bbv[4], pwv[4];
    #pragma unroll
    for (int jn = 0; jn < 4; ++jn) {
        int col = (w * 4 + jn) * 16 + lcol;
        bbv[jn] = P1b[col];
        pwv[jn] = P2w[col];
    }
    float p2b = P2b[0];
    const frag_ab* bp = (const frag_ab*)Bpack;

    int tile = blockIdx.x;
    if (tile >= ntiles) return;
    int buf = 0;

    // stage first tile
    {
        int q0 = tile * 32;
        for (int i = 0; i < 8; ++i) {
            int q = w * 8 + i;
            int qq = q0 + q;
            int qc = (qq < Q) ? qq : 0;
            int ua = u[qc], va = v[qc];
            const char* src = (lane < 32)
                ? (const char*)(X16 + (size_t)ua * D) + lane * 16
                : (const char*)(X16 + (size_t)va * D) + (lane - 32) * 16;
            async_ld16(src, (char*)UV[buf] + q * (UVPITCH * 2) + lane * 16);
        }
    }

    for (; tile < ntiles; tile += LP_BLOCKS) {
        int next = tile + LP_BLOCKS;
        if (next < ntiles) {
            // issue next tile's loads into the other buffer (overlaps this tile's MFMA wait)
            int q0n = next * 32;
            for (int i = 0; i < 8; ++i) {
                int q = w * 8 + i;
                int qq = q0n + q;
                int qc = (qq < Q) ? qq : 0;
                int ua = u[qc], va = v[qc];
                const char* src = (lane < 32)
                    ? (const char*)(X16 + (size_t)ua * D) + lane * 16
                    : (const char*)(X16 + (size_t)va * D) + (lane - 32) * 16;
                async_ld16(src, (char*)UV[buf ^ 1] + q * (UVPITCH * 2) + lane * 16);
            }
            asm volatile("s_waitcnt vmcnt(8)" ::: "memory");  // current tile's loads done; next's stay in flight
        } else {
            asm volatile("s_waitcnt vmcnt(0)" ::: "memory");
        }
        __syncthreads();

        // MFMA from UV[buf] — in-register product (r10 style)
        const unsigned short* UVb = UV[buf];
        frag_cd acc[2][4];
        #pragma unroll
        for (int m = 0; m < 2; ++m)
            #pragma unroll
            for (int jn = 0; jn < 4; ++jn) acc[m][jn] = (frag_cd){0.f, 0.f, 0.f, 0.f};

        for (int kt = 0; kt < 8; ++kt) {
            int ko = kt * 32 + quad * 8;
            union { frag_ab f; uint4 qv; } a[2];
            #pragma unroll
            for (int m = 0; m < 2; ++m) {
                const unsigned short* base = &UVb[(m * 16 + lcol) * UVPITCH];
                uint4 au = *(const uint4*)(base + ko);
                uint4 av = *(const uint4*)(base + 256 + ko);
                a[m].qv.x = bmul2t(au.x, av.x);
                a[m].qv.y = bmul2t(au.y, av.y);
                a[m].qv.z = bmul2t(au.z, av.z);
                a[m].qv.w = bmul2t(au.w, av.w);
            }
            #pragma unroll
            for (int jn = 0; jn < 4; ++jn) {
                frag_ab b = bp[((w * 4 + jn) * 8 + kt) * 64 + lane];
                acc[0][jn] = __builtin_amdgcn_mfma_f32_16x16x32_bf16(a[0].f, b, acc[0][jn], 0, 0, 0);
                acc[1][jn] = __builtin_amdgcn_mfma_f32_16x16x32_bf16(a[1].f, b, acc[1][jn], 0, 0, 0);
            }
        }

        // epilogue: relu(H+b1) . P2w
        float part[2][4] = {{0.f,0.f,0.f,0.f},{0.f,0.f,0.f,0.f}};
        #pragma unroll
        for (int jn = 0; jn < 4; ++jn) {
            #pragma unroll
            for (int m = 0; m < 2; ++m)
                #pragma unroll
                for (int r = 0; r < 4; ++r)
                    part[m][r] = fmaf(fmaxf(acc[m][jn][r] + bbv[jn], 0.f), pwv[jn], part[m][r]);
        }
        #pragma unroll
        for (int m = 0; m < 2; ++m)
            #pragma unroll
            for (int r = 0; r < 4; ++r) {
                float s = part[m][r];
                s += __shfl_down(s, 8);
                s += __shfl_down(s, 4);
                s += __shfl_down(s, 2);
                s += __shfl_down(s, 1);
                part[m][r] = s;
            }
        if (lcol == 0) {
            #pragma unroll
            for (int m = 0; m < 2; ++m)
                #pragma unroll
                for (int r = 0; r < 4; ++r)
                    red[w][m * 16 + quad * 4 + r] = part[m][r];
        }
        __syncthreads();

        if (t < 32) {
            int qq = tile * 32 + t;
            if (qq < Q) {
                float s = red[0][t] + red[1][t] + red[2][t] + red[3][t] + p2b;
                out[qq] = 1.0f / (1.0f + expf(-s));
            }
        }
        buf ^= 1;
    }
}

extern "C" void kernel_launch(void* const* d_in, const int* in_sizes, int n_in,
                              void* d_out, int out_size, void* d_ws, size_t ws_size,
                              hipStream_t stream) {
    const int*   edge_index = (const int*)d_in[0];
    const int*   edges      = (const int*)d_in[1];
    const float* emb        = (const float*)d_in[2];
    const float* W1         = (const float*)d_in[3];
    const float* b1         = (const float*)d_in[4];
    const float* W2         = (const float*)d_in[5];
    const float* b2         = (const float*)d_in[6];
    const float* P1w        = (const float*)d_in[7];
    const float* P1b        = (const float*)d_in[8];
    const float* P2w        = (const float*)d_in[9];
    const float* P2b        = (const float*)d_in[10];

    int E  = in_sizes[0] / 2;
    int Q  = in_sizes[1] / 2;
    int Nn = in_sizes[2] / D;

    const int* rowp = edge_index;
    const int* colp = edge_index + E;
    const int* uq   = edges;
    const int* vq   = edges + Q;
    float* out = (float*)d_out;

    // ---- workspace layout ----
    char* ws = (char*)d_ws;
    size_t off = 0;
    auto alloc = [&](size_t bytes) -> char* {
        char* p = ws + off;
        off = (off + bytes + 255) & ~(size_t)255;
        return p;
    };
    float*          dinv   = (float*)alloc((size_t)Nn * 4);
    int*            rowptr = (int*)  alloc(((size_t)Nn + 1) * 4);
    int*            ebuf   = (int*)  alloc((size_t)E * 4);
    unsigned short* BpW1   = (unsigned short*)alloc(65536 * 2);
    unsigned short* BpW2   = (unsigned short*)alloc(65536 * 2);
    unsigned short* BpP1   = (unsigned short*)alloc(65536 * 2);
    unsigned short* hbuf   = (unsigned short*)alloc((size_t)Nn * D * 2);  // bf16
    unsigned short* xbuf   = (unsigned short*)alloc((size_t)Nn * D * 2);  // bf16

    // CSR temporaries aliased into xbuf (dead until first k_agg writes it)
    int* degi  = (int*)xbuf;
    int* fill  = degi + Nn;
    int* bsums = degi + 2 * Nn;

    int nb;
    int nscan = (Nn + SCAN_CHUNK - 1) / SCAN_CHUNK;

    // CSR build
    nb = (2 * Nn + 255) / 256; k_zero_int<<<nb, 256, 0, stream>>>(degi, 2 * Nn);
    nb = (E + 255) / 256;      k_count_int<<<nb, 256, 0, stream>>>(rowp, degi, E);
    k_scan_block<<<nscan, 256, 0, stream>>>(degi, rowptr, bsums, Nn);
    k_scan_bsums<<<1, 256, 0, stream>>>(bsums, nscan);
    nb = (Nn + 255) / 256;     k_scan_add_dinv<<<nb, 256, 0, stream>>>(rowptr, bsums, degi, dinv, Nn, E);
    nb = (E + 255) / 256;      k_bucket<<<nb, 256, 0, stream>>>(rowp, colp, rowptr, fill, ebuf, E);

    // pack all three weights for MFMA B operand (one launch)
    k_packB3<<<768, 256, 0, stream>>>(W1, W2, P1w, BpW1, BpW2, BpP1);

    // conv1: h = emb @ W1 (MFMA 32-row tile, fp32 A) ; x1 = relu(norm-agg(h) + b1)  [bf16]
    nb = (Nn + 31) / 32; k_gemm_mfma<<<nb, 256, 0, stream>>>((const void*)emb, 1, BpW1, hbuf, Nn);
    nb = (Nn + 7) / 8;   k_agg<<<nb, 256, 0, stream>>>(hbuf, rowptr, ebuf, dinv, b1, xbuf, Nn, 1);

    // conv2: h = x1 @ W2 (MFMA 32-row tile, bf16 A) ; x2 = norm-agg(h) + b2          [bf16]
    nb = (Nn + 31) / 32; k_gemm_mfma<<<nb, 256, 0, stream>>>((const void*)xbuf, 0, BpW2, hbuf, Nn);
    nb = (Nn + 7) / 8;   k_agg<<<nb, 256, 0, stream>>>(hbuf, rowptr, ebuf, dinv, b2, xbuf, Nn, 0);

    // link predictor: persistent, double-buffered
    int ntiles = (Q + 31) / 32;
    int lpgrid = (ntiles < LP_BLOCKS) ? ntiles : LP_BLOCKS;
    k_linkpred<<<lpgrid, 256, 0, stream>>>(uq, vq, xbuf, BpP1, P1b, P2w, P2b, out, Q, ntiles);
}

// Round 14
// 440.670 us; speedup vs baseline: 1.0787x; 1.0787x over previous
//
#include <hip/hip_runtime.h>
#include <math.h>

#define D 256
#define SCAN_CHUNK 1024
#define GPITCH 264    // bf16 LDS pitch for MFMA A tiles (pad 8) — verified pattern r3-r10
#define UVPITCH 520   // fp16 pitch per query region: 256 u | 256 v | 8 pad (1040 B, 16B-aligned)

typedef __attribute__((ext_vector_type(8))) short frag_ab;     // 8 x 16-bit
typedef __attribute__((ext_vector_type(4))) float frag_cd;     // 4 fp32
typedef _Float16 frag_h __attribute__((ext_vector_type(8)));   // 8 fp16
typedef _Float16 h2 __attribute__((ext_vector_type(2)));
typedef __fp16 fp16x2 __attribute__((ext_vector_type(2)));

__device__ inline unsigned short f2b(float f) {
    unsigned int u = __float_as_uint(f);
    u += 0x7fffu + ((u >> 16) & 1u);
    return (unsigned short)(u >> 16);
}
__device__ inline float b2f(unsigned short h) {
    return __uint_as_float(((unsigned int)h) << 16);
}
__device__ inline unsigned short f2h(float f) {
    _Float16 h = (_Float16)f;
    union { _Float16 h; unsigned short s; } u; u.h = h;
    return u.s;
}
// pack two floats -> two fp16 (one v_cvt_pkrtz_f16_f32)
__device__ inline unsigned int pk_f16(float a, float b) {
    union { fp16x2 h; unsigned int u; } c;
    c.h = __builtin_amdgcn_cvt_pkrtz(a, b);
    return c.u;
}
// packed fp16 multiply: one v_pk_mul_f16
__device__ inline unsigned int h2mul(unsigned int a, unsigned int b) {
    union { unsigned int u; h2 h; } x, y, r;
    x.u = a; y.u = b;
    r.h = x.h * y.h;
    return r.u;
}

// async global->LDS, 16B per lane; LDS dest = wave-uniform base + lane*16
__device__ inline void async_ld16(const void* g, void* l) {
    __builtin_amdgcn_global_load_lds(
        (const __attribute__((address_space(1))) void*)g,
        (__attribute__((address_space(3))) void*)l,
        16, 0, 0);
}

// ---------- zero int buffer ----------
__global__ void k_zero_int(int* p, int n) {
    int i = blockIdx.x * 256 + threadIdx.x;
    if (i < n) p[i] = 0;
}

// ---------- int degree count ----------
__global__ void k_count_int(const int* __restrict__ row, int* deg, int E) {
    int e = blockIdx.x * 256 + threadIdx.x;
    if (e < E) atomicAdd(&deg[row[e]], 1);
}

// ---------- prefix scan (3 stages); excl written into rowptr ----------
__global__ __launch_bounds__(256) void k_scan_block(const int* __restrict__ deg, int* __restrict__ excl,
                                                    int* __restrict__ bsums, int n) {
    __shared__ int s[256];
    int blk = blockIdx.x, t = threadIdx.x;
    int base = blk * SCAN_CHUNK + t * 4;
    int v0 = (base + 0 < n) ? deg[base + 0] : 0;
    int v1 = (base + 1 < n) ? deg[base + 1] : 0;
    int v2 = (base + 2 < n) ? deg[base + 2] : 0;
    int v3 = (base + 3 < n) ? deg[base + 3] : 0;
    int tsum = v0 + v1 + v2 + v3;
    s[t] = tsum;
    __syncthreads();
    for (int off = 1; off < 256; off <<= 1) {
        int x = (t >= off) ? s[t - off] : 0;
        __syncthreads();
        s[t] += x;
        __syncthreads();
    }
    int run = s[t] - tsum;
    if (t == 255) bsums[blk] = s[255];
    if (base + 0 < n) excl[base + 0] = run;
    run += v0;
    if (base + 1 < n) excl[base + 1] = run;
    run += v1;
    if (base + 2 < n) excl[base + 2] = run;
    run += v2;
    if (base + 3 < n) excl[base + 3] = run;
}

__global__ __launch_bounds__(256) void k_scan_bsums(int* bsums, int nb) {
    __shared__ int s[256];
    int t = threadIdx.x;
    int v = (t < nb) ? bsums[t] : 0;
    s[t] = v;
    __syncthreads();
    for (int off = 1; off < 256; off <<= 1) {
        int x = (t >= off) ? s[t - off] : 0;
        __syncthreads();
        s[t] += x;
        __syncthreads();
    }
    if (t < nb) bsums[t] = s[t] - v;
}

// fused: rowptr[i] += bsums[i/SCAN_CHUNK]  AND  dinv[i] = rsqrt(deg[i]+1)
__global__ void k_scan_add_dinv(int* __restrict__ rowptr, const int* __restrict__ bsums,
                                const int* __restrict__ deg, float* __restrict__ dinv,
                                int n, int total) {
    int i = blockIdx.x * 256 + threadIdx.x;
    if (i < n) {
        rowptr[i] += bsums[i / SCAN_CHUNK];
        dinv[i] = rsqrtf((float)(deg[i] + 1));
    }
    if (i == 0) rowptr[n] = total;
}

// ---------- bucket edges into CSR ----------
__global__ void k_bucket(const int* __restrict__ row, const int* __restrict__ col,
                         const int* __restrict__ rowptr, int* __restrict__ fill,
                         int* __restrict__ ebuf, int E) {
    int e = blockIdx.x * 256 + threadIdx.x;
    if (e >= E) return;
    int r = row[e];
    int pos = atomicAdd(&fill[r], 1);
    ebuf[rowptr[r] + pos] = col[e];
}

// ---------- pack three fp32 [k][n] weights into MFMA B-fragment order ----------
// which 0/1 (W1,W2): bf16.  which 2 (P1w): fp16.
__global__ void k_packB3(const float* __restrict__ Wa, const float* __restrict__ Wb,
                         const float* __restrict__ Wc,
                         unsigned short* __restrict__ Ba, unsigned short* __restrict__ Bb,
                         unsigned short* __restrict__ Bc) {
    int which = blockIdx.x >> 8;
    int i = (blockIdx.x & 255) * 256 + threadIdx.x;   // 65536 per weight
    const float* W = (which == 0) ? Wa : (which == 1) ? Wb : Wc;
    unsigned short* Bp = (which == 0) ? Ba : (which == 1) ? Bb : Bc;
    int ntile = i >> 12;
    int kt = (i >> 9) & 7;
    int lane = (i >> 3) & 63;
    int j = i & 7;
    int k = kt * 32 + (lane >> 4) * 8 + j;
    int n = ntile * 16 + (lane & 15);
    float wv = W[k * D + n];
    Bp[i] = (which == 2) ? f2h(wv) : f2b(wv);
}

// ---------- MFMA GEMM: 32-row tile (r10 — best measured). bf16 in/out ----------
__global__ __launch_bounds__(256) void k_gemm_mfma(const void* __restrict__ X, int xIsF32,
                                                   const unsigned short* __restrict__ Bpack,
                                                   unsigned short* __restrict__ H, int nrows) {
    __shared__ unsigned short As[32 * GPITCH];
    int t = threadIdx.x;
    int rowBase = blockIdx.x * 32;

    {
        int half = t >> 7;
        int cpair = t & 127;
        for (int qi = 0; qi < 32; qi += 2) {
            int q = qi + half;
            int r = rowBase + q;
            unsigned int val = 0;
            if (r < nrows) {
                if (xIsF32) {
                    const float* xr = (const float*)X + (size_t)r * D + cpair * 2;
                    val = (unsigned int)f2b(xr[0]) | ((unsigned int)f2b(xr[1]) << 16);
                } else {
                    val = ((const unsigned int*)((const unsigned short*)X + (size_t)r * D))[cpair];
                }
            }
            *(unsigned int*)&As[q * GPITCH + cpair * 2] = val;
        }
    }
    __syncthreads();

    int w = t >> 6, lane = t & 63;
    int mtile = w >> 1;
    int nhalf = w & 1;
    int quad = lane >> 4, lcol = lane & 15;

    frag_cd acc[8];
    #pragma unroll
    for (int n = 0; n < 8; ++n) acc[n] = (frag_cd){0.f, 0.f, 0.f, 0.f};

    const frag_ab* bp = (const frag_ab*)Bpack;
    for (int kt = 0; kt < 8; ++kt) {
        frag_ab a = *(const frag_ab*)&As[(mtile * 16 + lcol) * GPITCH + kt * 32 + quad * 8];
        #pragma unroll
        for (int n = 0; n < 8; ++n) {
            frag_ab b = bp[((nhalf * 8 + n) * 8 + kt) * 64 + lane];
            acc[n] = __builtin_amdgcn_mfma_f32_16x16x32_bf16(a, b, acc[n], 0, 0, 0);
        }
    }

    #pragma unroll
    for (int n = 0; n < 8; ++n) {
        int col = (nhalf * 8 + n) * 16 + lcol;
        #pragma unroll
        for (int r = 0; r < 4; ++r) {
            int row = rowBase + mtile * 16 + quad * 4 + r;
            if (row < nrows) H[(size_t)row * D + col] = f2b(acc[n][r]);
        }
    }
}

// ---------- aggregate by gather: 2 nodes per wave, 32 lanes (16B) per node ----------
// mode 1: relu, bf16 out (feeds gemm2).  mode 0: no relu, FP16 out (feeds linkpred).
__device__ inline void fma8(uint4 p, float nw, float* a) {
    a[0] = fmaf(b2f((unsigned short)(p.x & 0xffffu)), nw, a[0]);
    a[1] = fmaf(b2f((unsigned short)(p.x >> 16)),     nw, a[1]);
    a[2] = fmaf(b2f((unsigned short)(p.y & 0xffffu)), nw, a[2]);
    a[3] = fmaf(b2f((unsigned short)(p.y >> 16)),     nw, a[3]);
    a[4] = fmaf(b2f((unsigned short)(p.z & 0xffffu)), nw, a[4]);
    a[5] = fmaf(b2f((unsigned short)(p.z >> 16)),     nw, a[5]);
    a[6] = fmaf(b2f((unsigned short)(p.w & 0xffffu)), nw, a[6]);
    a[7] = fmaf(b2f((unsigned short)(p.w >> 16)),     nw, a[7]);
}

__global__ __launch_bounds__(256) void k_agg(const unsigned short* __restrict__ Hh,
                                             const int* __restrict__ rowptr, const int* __restrict__ ebuf,
                                             const float* __restrict__ dinv, const float* __restrict__ b,
                                             unsigned short* __restrict__ Xo, int n, int relu) {
    int w = threadIdx.x >> 6, lane = threadIdx.x & 63;
    int half = lane >> 5, sub = lane & 31;
    int node = (blockIdx.x * 4 + w) * 2 + half;
    if (node >= n) return;
    int c8 = sub * 8;

    float dn = dinv[node];
    float self = dn * dn;

    float acc[8];
    {
        uint4 hp = *(const uint4*)&Hh[(size_t)node * D + c8];
        float4 b0 = *(const float4*)&b[c8];
        float4 b1 = *(const float4*)&b[c8 + 4];
        acc[0] = b0.x; acc[1] = b0.y; acc[2] = b0.z; acc[3] = b0.w;
        acc[4] = b1.x; acc[5] = b1.y; acc[6] = b1.z; acc[7] = b1.w;
        fma8(hp, self, acc);
    }

    int beg = rowptr[node], end = rowptr[node + 1];
    int j = beg;
    for (; j + 3 < end; j += 4) {
        int cA = ebuf[j], cB = ebuf[j + 1], cC = ebuf[j + 2], cD = ebuf[j + 3];
        float nA = dn * dinv[cA], nB = dn * dinv[cB], nC = dn * dinv[cC], nD = dn * dinv[cD];
        uint4 pA = *(const uint4*)&Hh[(size_t)cA * D + c8];
        uint4 pB = *(const uint4*)&Hh[(size_t)cB * D + c8];
        uint4 pC = *(const uint4*)&Hh[(size_t)cC * D + c8];
        uint4 pD = *(const uint4*)&Hh[(size_t)cD * D + c8];
        fma8(pA, nA, acc);
        fma8(pB, nB, acc);
        fma8(pC, nC, acc);
        fma8(pD, nD, acc);
    }
    for (; j < end; ++j) {
        int cA = ebuf[j];
        uint4 pA = *(const uint4*)&Hh[(size_t)cA * D + c8];
        fma8(pA, dn * dinv[cA], acc);
    }
    uint4 pk;
    if (relu) {
        #pragma unroll
        for (int i = 0; i < 8; ++i) acc[i] = fmaxf(acc[i], 0.f);
        pk.x = (unsigned int)f2b(acc[0]) | ((unsigned int)f2b(acc[1]) << 16);
        pk.y = (unsigned int)f2b(acc[2]) | ((unsigned int)f2b(acc[3]) << 16);
        pk.z = (unsigned int)f2b(acc[4]) | ((unsigned int)f2b(acc[5]) << 16);
        pk.w = (unsigned int)f2b(acc[6]) | ((unsigned int)f2b(acc[7]) << 16);
    } else {
        pk.x = pk_f16(acc[0], acc[1]);
        pk.y = pk_f16(acc[2], acc[3]);
        pk.z = pk_f16(acc[4], acc[5]);
        pk.w = pk_f16(acc[6], acc[7]);
    }
    *(uint4*)&Xo[(size_t)node * D + c8] = pk;
}

// ---------- link predictor: r10 structure, FP16 data path ----------
// stage 0: async staging of u|v fp16 rows. stage 1: MFMA f16 with register-built
// A-frags — product is v_pk_mul_f16 (1 op per 2 elems vs 7-op bf16 emulation).
__global__ __launch_bounds__(256) void k_linkpred(const int* __restrict__ u, const int* __restrict__ v,
                                                  const unsigned short* __restrict__ X16,
                                                  const unsigned short* __restrict__ Bpack,
                                                  const float* __restrict__ P1b,
                                                  const float* __restrict__ P2w, const float* __restrict__ P2b,
                                                  float* __restrict__ out, int Q) {
    __shared__ unsigned short UV[32 * UVPITCH];   // 33,280 B
    __shared__ float red[4][32];

    int t = threadIdx.x;
    int w = t >> 6, lane = t & 63;
    int quad = lane >> 4, lcol = lane & 15;
    int q0 = blockIdx.x * 32;

    // ---- stage 0: async gather of endpoint rows (8 q per wave, 16B/lane) ----
    for (int i = 0; i < 8; ++i) {
        int q = w * 8 + i;
        int qq = q0 + q;
        int qc = (qq < Q) ? qq : 0;
        int ua = u[qc], va = v[qc];
        const char* src = (lane < 32)
            ? (const char*)(X16 + (size_t)ua * D) + lane * 16
            : (const char*)(X16 + (size_t)va * D) + (lane - 32) * 16;
        async_ld16(src, (char*)UV + q * (UVPITCH * 2) + lane * 16);
    }
    asm volatile("s_waitcnt vmcnt(0)" ::: "memory");
    __syncthreads();

    // ---- stage 1: MFMA f16 with register-built A-frags ----
    frag_cd acc[2][4];
    #pragma unroll
    for (int m = 0; m < 2; ++m)
        #pragma unroll
        for (int jn = 0; jn < 4; ++jn) acc[m][jn] = (frag_cd){0.f, 0.f, 0.f, 0.f};

    const frag_h* bp = (const frag_h*)Bpack;
    for (int kt = 0; kt < 8; ++kt) {
        int ko = kt * 32 + quad * 8;
        union { frag_h f; uint4 qv; } a[2];
        #pragma unroll
        for (int m = 0; m < 2; ++m) {
            const unsigned short* base = &UV[(m * 16 + lcol) * UVPITCH];
            uint4 au = *(const uint4*)(base + ko);
            uint4 av = *(const uint4*)(base + 256 + ko);
            a[m].qv.x = h2mul(au.x, av.x);
            a[m].qv.y = h2mul(au.y, av.y);
            a[m].qv.z = h2mul(au.z, av.z);
            a[m].qv.w = h2mul(au.w, av.w);
        }
        #pragma unroll
        for (int jn = 0; jn < 4; ++jn) {
            frag_h b = bp[((w * 4 + jn) * 8 + kt) * 64 + lane];
            acc[0][jn] = __builtin_amdgcn_mfma_f32_16x16x32_f16(a[0].f, b, acc[0][jn], 0, 0, 0);
            acc[1][jn] = __builtin_amdgcn_mfma_f32_16x16x32_f16(a[1].f, b, acc[1][jn], 0, 0, 0);
        }
    }

    // ---- epilogue: relu(H+b1) . P2w, partial over this wave's 4 ntiles ----
    float part[2][4] = {{0.f,0.f,0.f,0.f},{0.f,0.f,0.f,0.f}};
    #pragma unroll
    for (int jn = 0; jn < 4; ++jn) {
        int col = (w * 4 + jn) * 16 + lcol;
        float bb = P1b[col];
        float pw = P2w[col];
        #pragma unroll
        for (int m = 0; m < 2; ++m)
            #pragma unroll
            for (int r = 0; r < 4; ++r)
                part[m][r] = fmaf(fmaxf(acc[m][jn][r] + bb, 0.f), pw, part[m][r]);
    }
    #pragma unroll
    for (int m = 0; m < 2; ++m)
        #pragma unroll
        for (int r = 0; r < 4; ++r) {
            float s = part[m][r];
            s += __shfl_down(s, 8);
            s += __shfl_down(s, 4);
            s += __shfl_down(s, 2);
            s += __shfl_down(s, 1);
            part[m][r] = s;
        }
    if (lcol == 0) {
        #pragma unroll
        for (int m = 0; m < 2; ++m)
            #pragma unroll
            for (int r = 0; r < 4; ++r)
                red[w][m * 16 + quad * 4 + r] = part[m][r];
    }
    __syncthreads();

    if (t < 32) {
        int qq = q0 + t;
        if (qq < Q) {
            float s = red[0][t] + red[1][t] + red[2][t] + red[3][t] + P2b[0];
            out[qq] = 1.0f / (1.0f + expf(-s));
        }
    }
}

extern "C" void kernel_launch(void* const* d_in, const int* in_sizes, int n_in,
                              void* d_out, int out_size, void* d_ws, size_t ws_size,
                              hipStream_t stream) {
    const int*   edge_index = (const int*)d_in[0];
    const int*   edges      = (const int*)d_in[1];
    const float* emb        = (const float*)d_in[2];
    const float* W1         = (const float*)d_in[3];
    const float* b1         = (const float*)d_in[4];
    const float* W2         = (const float*)d_in[5];
    const float* b2         = (const float*)d_in[6];
    const float* P1w        = (const float*)d_in[7];
    const float* P1b        = (const float*)d_in[8];
    const float* P2w        = (const float*)d_in[9];
    const float* P2b        = (const float*)d_in[10];

    int E  = in_sizes[0] / 2;
    int Q  = in_sizes[1] / 2;
    int Nn = in_sizes[2] / D;

    const int* rowp = edge_index;
    const int* colp = edge_index + E;
    const int* uq   = edges;
    const int* vq   = edges + Q;
    float* out = (float*)d_out;

    // ---- workspace layout ----
    char* ws = (char*)d_ws;
    size_t off = 0;
    auto alloc = [&](size_t bytes) -> char* {
        char* p = ws + off;
        off = (off + bytes + 255) & ~(size_t)255;
        return p;
    };
    float*          dinv   = (float*)alloc((size_t)Nn * 4);
    int*            rowptr = (int*)  alloc(((size_t)Nn + 1) * 4);
    int*            ebuf   = (int*)  alloc((size_t)E * 4);
    unsigned short* BpW1   = (unsigned short*)alloc(65536 * 2);
    unsigned short* BpW2   = (unsigned short*)alloc(65536 * 2);
    unsigned short* BpP1   = (unsigned short*)alloc(65536 * 2);
    unsigned short* hbuf   = (unsigned short*)alloc((size_t)Nn * D * 2);  // bf16
    unsigned short* xbuf   = (unsigned short*)alloc((size_t)Nn * D * 2);  // bf16 (conv1) / fp16 (conv2)

    // CSR temporaries aliased into xbuf (dead until first k_agg writes it)
    int* degi  = (int*)xbuf;
    int* fill  = degi + Nn;
    int* bsums = degi + 2 * Nn;

    int nb;
    int nscan = (Nn + SCAN_CHUNK - 1) / SCAN_CHUNK;

    // CSR build
    nb = (2 * Nn + 255) / 256; k_zero_int<<<nb, 256, 0, stream>>>(degi, 2 * Nn);
    nb = (E + 255) / 256;      k_count_int<<<nb, 256, 0, stream>>>(rowp, degi, E);
    k_scan_block<<<nscan, 256, 0, stream>>>(degi, rowptr, bsums, Nn);
    k_scan_bsums<<<1, 256, 0, stream>>>(bsums, nscan);
    nb = (Nn + 255) / 256;     k_scan_add_dinv<<<nb, 256, 0, stream>>>(rowptr, bsums, degi, dinv, Nn, E);
    nb = (E + 255) / 256;      k_bucket<<<nb, 256, 0, stream>>>(rowp, colp, rowptr, fill, ebuf, E);

    // pack weights: W1/W2 bf16, P1w fp16 (one launch)
    k_packB3<<<768, 256, 0, stream>>>(W1, W2, P1w, BpW1, BpW2, BpP1);

    // conv1: h = emb @ W1 (MFMA, fp32 A) ; x1 = relu(norm-agg(h) + b1)  [bf16]
    nb = (Nn + 31) / 32; k_gemm_mfma<<<nb, 256, 0, stream>>>((const void*)emb, 1, BpW1, hbuf, Nn);
    nb = (Nn + 7) / 8;   k_agg<<<nb, 256, 0, stream>>>(hbuf, rowptr, ebuf, dinv, b1, xbuf, Nn, 1);

    // conv2: h = x1 @ W2 (MFMA, bf16 A) ; x2 = norm-agg(h) + b2          [FP16 out]
    nb = (Nn + 31) / 32; k_gemm_mfma<<<nb, 256, 0, stream>>>((const void*)xbuf, 0, BpW2, hbuf, Nn);
    nb = (Nn + 7) / 8;   k_agg<<<nb, 256, 0, stream>>>(hbuf, rowptr, ebuf, dinv, b2, xbuf, Nn, 0);

    // link predictor (fp16 data path, r10 structure)
    nb = (Q + 31) / 32;  k_linkpred<<<nb, 256, 0, stream>>>(uq, vq, xbuf, BpP1, P1b, P2w, P2b, out, Q);
}